// Round 8
// baseline (265.920 us; speedup 1.0000x reference)
//
#include <hip/hip_runtime.h>
#include <hip/hip_bf16.h>
#include <stdint.h>
#include <float.h>

// VQ quantize: z[65536,256] f32, weight[1024,256] f32.
// ref (numpy fp32): d = fl32(fl32(A - 2*B) + C); idx = argmax(-d) (first-index ties).
// Outputs (float32, concat): quantized [65536*256], indices [65536].
//
// Pipeline:
//   1) vq_prep: fused {init cnt/packed, z->bf16, w->bf16, Cn=|w|^2 exact}
//   2) vq_screen: bf16 MFMA GEMM screen. R10: 512-thread blocks (8 waves,
//      wave tile 32x64, vmcnt(4), 16 waves/CU -- was 8; R7 showed 19% MfmaUtil
//      at 5x the LDS floor = latency-bound, not pipe-bound). Epilogue moved
//      after the trailing barrier (registers+Cs only) to overlap next stage-wait.
//   3) vq_candx: cand+exact MERGED. Pipeline identical to proven cand; on
//      threshold hit, inline bit-exact numpy-fp32 eval (pairwise A, seq-k fma B)
//      + atomicMin packed (ordered-d, code). No pairs buffer, no pcnt, one
//      less launch. ~1 hit/thread/job => divergence negligible.
//   4) vq_unpack: separate kernel (R5 lesson: packed lives in d_out; must be
//      consumed before vq_gather overwrites it).
//   5) vq_gather.

constexpr int NROWS = 65536;
constexpr int D     = 256;
constexpr int CODES = 1024;

constexpr float TAU_SCREEN = 2.5e-4f;

typedef __attribute__((ext_vector_type(8))) short short8;   // 8 bf16 = 4 VGPR
typedef __attribute__((ext_vector_type(4))) float f32x4;

// global -> LDS async 16B/lane: per-lane global src, wave-uniform LDS base,
// HW writes lane l -> base + l*16 (m97/m104 semantics).
__device__ __forceinline__ void gl2lds16(const unsigned short* g, unsigned short* l) {
    __builtin_amdgcn_global_load_lds(
        (const __attribute__((address_space(1))) void*)g,
        (__attribute__((address_space(3))) void*)l, 16, 0, 0);
}

// ---------------- fp32 -> bf16 (RNE) ----------------
__device__ __forceinline__ unsigned short f2bf(float x) {
    union { __hip_bfloat16 h; unsigned short u; } c;
    c.h = __float2bfloat16(x);
    return c.u;
}

__device__ __forceinline__ void cvt8(const float* __restrict__ src,
                                     unsigned short* __restrict__ dst, int i) {
    const float4* s = (const float4*)src + (size_t)i * 2;
    float4 a = s[0], b = s[1];
    union { unsigned short u[8]; uint4 v; } p;
    p.u[0] = f2bf(a.x); p.u[1] = f2bf(a.y); p.u[2] = f2bf(a.z); p.u[3] = f2bf(a.w);
    p.u[4] = f2bf(b.x); p.u[5] = f2bf(b.y); p.u[6] = f2bf(b.z); p.u[7] = f2bf(b.w);
    *(uint4*)(dst + (size_t)i * 8) = p.v;
}

// ---------------- exact numpy-fp32 distance (proven chain, verbatim) ----------------
__device__ __forceinline__ float np_exact_d(const float* __restrict__ z,
                                            const float* __restrict__ w,
                                            const float* __restrict__ Cn,
                                            int row, int code) {
    const float4* zp = (const float4*)(z + (size_t)row * D);
    const float4* wp = (const float4*)(w + (size_t)code * D);
    float B = 0.f;
    float res[2];
    #pragma unroll
    for (int b = 0; b < 2; ++b) {
        float r[8];
        #pragma unroll
        for (int j = 0; j < 8; ++j) r[j] = 0.f;
        #pragma unroll 4
        for (int mm = 0; mm < 16; ++mm) {
            const float4 z0 = zp[b * 32 + mm * 2];
            const float4 z1 = zp[b * 32 + mm * 2 + 1];
            const float4 w0 = wp[b * 32 + mm * 2];
            const float4 w1 = wp[b * 32 + mm * 2 + 1];
            r[0] = __fadd_rn(r[0], __fmul_rn(z0.x, z0.x));
            r[1] = __fadd_rn(r[1], __fmul_rn(z0.y, z0.y));
            r[2] = __fadd_rn(r[2], __fmul_rn(z0.z, z0.z));
            r[3] = __fadd_rn(r[3], __fmul_rn(z0.w, z0.w));
            r[4] = __fadd_rn(r[4], __fmul_rn(z1.x, z1.x));
            r[5] = __fadd_rn(r[5], __fmul_rn(z1.y, z1.y));
            r[6] = __fadd_rn(r[6], __fmul_rn(z1.z, z1.z));
            r[7] = __fadd_rn(r[7], __fmul_rn(z1.w, z1.w));
            B = fmaf(z0.x, w0.x, B); B = fmaf(z0.y, w0.y, B);
            B = fmaf(z0.z, w0.z, B); B = fmaf(z0.w, w0.w, B);
            B = fmaf(z1.x, w1.x, B); B = fmaf(z1.y, w1.y, B);
            B = fmaf(z1.z, w1.z, B); B = fmaf(z1.w, w1.w, B);
        }
        res[b] = __fadd_rn(__fadd_rn(__fadd_rn(r[0], r[1]), __fadd_rn(r[2], r[3])),
                           __fadd_rn(__fadd_rn(r[4], r[5]), __fadd_rn(r[6], r[7])));
    }
    const float A = __fadd_rn(res[0], res[1]);
    return __fadd_rn(__fsub_rn(A, __fmul_rn(2.0f, B)), Cn[code]);
}

// ---------------- fused prep ----------------
// blocks [0,8192): z->bf16 | [8192,8320): w->bf16 | [8320,8324): rownorm |
// [8324,8580): packed init + cnt. rownorm in EXACT numpy pairwise order.
__global__ __launch_bounds__(256) void vq_prep(const float* __restrict__ z,
                                               unsigned short* __restrict__ zbf,
                                               const float* __restrict__ w,
                                               unsigned short* __restrict__ wbf,
                                               float* __restrict__ Cn,
                                               int* __restrict__ cnt,
                                               unsigned long long* __restrict__ packed) {
    const int b = blockIdx.x;
    const int t = threadIdx.x;
    if (b < 8192) {
        cvt8(z, zbf, b * 256 + t);
    } else if (b < 8320) {
        cvt8(w, wbf, (b - 8192) * 256 + t);
    } else if (b < 8324) {
        const int row = (b - 8320) * 256 + t;
        const float4* p = (const float4*)(w + (size_t)row * D);
        float res[2];
        #pragma unroll
        for (int h = 0; h < 2; ++h) {
            float r[8];
            #pragma unroll
            for (int j = 0; j < 8; ++j) r[j] = 0.f;
            #pragma unroll 4
            for (int mm = 0; mm < 16; ++mm) {
                const float4 v0 = p[h * 32 + mm * 2];
                const float4 v1 = p[h * 32 + mm * 2 + 1];
                r[0] = __fadd_rn(r[0], __fmul_rn(v0.x, v0.x));
                r[1] = __fadd_rn(r[1], __fmul_rn(v0.y, v0.y));
                r[2] = __fadd_rn(r[2], __fmul_rn(v0.z, v0.z));
                r[3] = __fadd_rn(r[3], __fmul_rn(v0.w, v0.w));
                r[4] = __fadd_rn(r[4], __fmul_rn(v1.x, v1.x));
                r[5] = __fadd_rn(r[5], __fmul_rn(v1.y, v1.y));
                r[6] = __fadd_rn(r[6], __fmul_rn(v1.z, v1.z));
                r[7] = __fadd_rn(r[7], __fmul_rn(v1.w, v1.w));
            }
            res[h] = __fadd_rn(__fadd_rn(__fadd_rn(r[0], r[1]), __fadd_rn(r[2], r[3])),
                               __fadd_rn(__fadd_rn(r[4], r[5]), __fadd_rn(r[6], r[7])));
        }
        Cn[row] = __fadd_rn(res[0], res[1]);
    } else {
        const int i = (b - 8324) * 256 + t;
        packed[i] = ~0ull;
        if (i == 0) *cnt = 0;
    }
}

// ---------------- bf16 MFMA screen (R10: 8-wave blocks, counted vmcnt) ----------------
// 128 rows x 1024 codes per block; 32 steps (nb-major, ks-minor), dbuf LDS.
// 8 waves: wave wv -> rows [ (wv>>1)*32, +32 ) x cols [ (wv&1)*64, +64 ) per nb.
// Staging: 32 units of 1KB (16 z + 16 w); wave wv stages units 4wv..4wv+3;
// LINEAR LDS dest + pre-swizzled global source (row bases multiples of 8, so
// the read-side ch^(m&7) XOR is unchanged -- verified geometry).
__global__ __launch_bounds__(512, 4) void vq_screen(const unsigned short* __restrict__ zbf,
                                                    const unsigned short* __restrict__ wbf,
                                                    const float* __restrict__ Cn,
                                                    int* __restrict__ idx_out,
                                                    int* __restrict__ flagged,
                                                    int* __restrict__ cnt,
                                                    float* __restrict__ m1_out) {
    __shared__ unsigned short zT[2][128 * 64];
    __shared__ unsigned short wT[2][128 * 64];
    __shared__ float Cs[1024];
    __shared__ float rm1s[2][128];
    __shared__ float rm2s[2][128];
    __shared__ int   ris[2][128];

    const int t    = threadIdx.x;
    const int wv   = t >> 6;          // wave 0..7
    const int l    = t & 63;
    const int wm   = wv >> 1;         // row quarter 0..3
    const int wn   = wv & 1;          // col half
    const int m    = l & 15;
    const int quad = l >> 4;
    const int row0 = blockIdx.x * 128;

    // staging geometry (per-lane within a 1KB unit = 8 rows x 64 elems)
    const int  srow8   = l >> 3;
    const int  schunk  = (l & 7) ^ srow8;
    const size_t laneoff = (size_t)srow8 * D + schunk * 8;

    for (int i = t; i < 1024; i += 512) Cs[i] = Cn[i];

    float m1[2][4], m2[2][4];
    int   bi[2][4];
    f32x4 acc[2][4];
    #pragma unroll
    for (int mi = 0; mi < 2; ++mi)
        #pragma unroll
        for (int r = 0; r < 4; ++r) {
            m1[mi][r] = FLT_MAX; m2[mi][r] = FLT_MAX; bi[mi][r] = 0;
            acc[mi][r] = (f32x4){0.f, 0.f, 0.f, 0.f};
        }

    #define STAGE(s_, buf_) do {                                                    \
        const int nb_ = (s_) >> 2, ks_ = (s_) & 3;                                  \
        _Pragma("unroll")                                                           \
        for (int i_ = 0; i_ < 4; ++i_) {                                            \
            const int u_ = wv * 4 + i_;                                             \
            if (u_ < 16)                                                            \
                gl2lds16(zbf + (size_t)(row0 + u_ * 8) * D + ks_ * 64 + laneoff,    \
                         &zT[buf_][u_ * 512]);                                      \
            else                                                                    \
                gl2lds16(wbf + (size_t)(nb_ * 128 + (u_ - 16) * 8) * D + ks_ * 64   \
                             + laneoff,                                             \
                         &wT[buf_][(u_ - 16) * 512]);                               \
        }                                                                           \
    } while (0)

    STAGE(0, 0);

    for (int s = 0; s < 32; ++s) {
        const int cur = s & 1;
        if (s < 31) {
            STAGE(s + 1, cur ^ 1);
            asm volatile("s_waitcnt vmcnt(4) lgkmcnt(0)" ::: "memory");
        } else {
            asm volatile("s_waitcnt vmcnt(0) lgkmcnt(0)" ::: "memory");
        }
        asm volatile("s_barrier" ::: "memory");

        #pragma unroll
        for (int kk = 0; kk < 2; ++kk) {
            short8 a[2], b[4];
            const int ch = kk * 4 + quad;
            const int co = (ch ^ (m & 7)) * 8;
            #pragma unroll
            for (int mi = 0; mi < 2; ++mi)
                a[mi] = *(const short8*)&zT[cur][(wm * 32 + mi * 16 + m) * 64 + co];
            #pragma unroll
            for (int ni = 0; ni < 4; ++ni)
                b[ni] = *(const short8*)&wT[cur][(wn * 64 + ni * 16 + m) * 64 + co];
            #pragma unroll
            for (int mi = 0; mi < 2; ++mi)
                #pragma unroll
                for (int ni = 0; ni < 4; ++ni)
                    acc[mi][ni] = __builtin_amdgcn_mfma_f32_16x16x32_bf16(
                        a[mi], b[ni], acc[mi][ni], 0, 0, 0);
        }
        asm volatile("s_barrier" ::: "memory");

        if ((s & 3) == 3) {          // nb complete: registers + Cs only -> after barrier
            const int nb = s >> 2;
            #pragma unroll
            for (int ni = 0; ni < 4; ++ni) {
                const int code = nb * 128 + wn * 64 + ni * 16 + m;
                const float c  = Cs[code];
                #pragma unroll
                for (int mi = 0; mi < 2; ++mi)
                    #pragma unroll
                    for (int r = 0; r < 4; ++r) {
                        const float v = fmaf(-2.0f, acc[mi][ni][r], c);
                        if (v < m1[mi][r]) { m2[mi][r] = m1[mi][r]; m1[mi][r] = v; bi[mi][r] = code; }
                        else if (v < m2[mi][r]) m2[mi][r] = v;
                        acc[mi][ni][r] = 0.f;
                    }
            }
        }
    }
    #undef STAGE

    // reduce across the 16 col-lanes (xor 1,2,4,8 varies l&15 only).
    #pragma unroll
    for (int mi = 0; mi < 2; ++mi)
        #pragma unroll
        for (int r = 0; r < 4; ++r) {
            float a1 = m1[mi][r], a2 = m2[mi][r];
            int   ai = bi[mi][r];
            #pragma unroll
            for (int off = 1; off <= 8; off <<= 1) {
                float o1 = __shfl_xor(a1, off, 64);
                float o2 = __shfl_xor(a2, off, 64);
                int   oi = __shfl_xor(ai, off, 64);
                float n2 = fminf(a2, o2);
                if (o1 < a1) { n2 = fminf(n2, a1); a1 = o1; ai = oi; }
                else n2 = fminf(n2, o1);
                a2 = n2;
            }
            m1[mi][r] = a1; m2[mi][r] = a2; bi[mi][r] = ai;
        }

    if (m == 0) {
        #pragma unroll
        for (int mi = 0; mi < 2; ++mi)
            #pragma unroll
            for (int r = 0; r < 4; ++r) {
                const int rl = wm * 32 + mi * 16 + quad * 4 + r;
                rm1s[wn][rl] = m1[mi][r];
                rm2s[wn][rl] = m2[mi][r];
                ris[wn][rl]  = bi[mi][r];
            }
    }
    __syncthreads();
    if (t < 128) {
        float a1 = rm1s[0][t], a2 = rm2s[0][t];
        int   ai = ris[0][t];
        const float o1 = rm1s[1][t], o2 = rm2s[1][t];
        const int   oi = ris[1][t];
        float n2 = fminf(a2, o2);
        if (o1 < a1) { n2 = fminf(n2, a1); a1 = o1; ai = oi; }
        else n2 = fminf(n2, o1);
        a2 = n2;
        const int row = row0 + t;
        idx_out[row] = ai;
        m1_out[row]  = a1;
        if (a2 - a1 < TAU_SCREEN) {
            int p = atomicAdd(cnt, 1);
            flagged[p] = row;
        }
    }
}

// ---------------- cand+exact merged (tile x nb jobs, counted-vmcnt) ----------------
// Job = (128 gathered flagged rows) x (one 128-code nb). On threshold hit,
// inline bit-exact numpy-fp32 eval + atomicMin packed (ordered-d, code) --
// order-independent, no pairs buffer. Bitwise-identical MFMA order to vq_screen.
__global__ __launch_bounds__(256, 2) void vq_candx(const unsigned short* __restrict__ zbf,
                                                   const unsigned short* __restrict__ wbf,
                                                   const float* __restrict__ Cn,
                                                   const float* __restrict__ m1g,
                                                   const int* __restrict__ flagged,
                                                   const int* __restrict__ cnt,
                                                   const float* __restrict__ z,
                                                   const float* __restrict__ w,
                                                   unsigned long long* __restrict__ packed) {
    __shared__ unsigned short zT[2][128 * 64];
    __shared__ unsigned short wT[2][128 * 64];
    __shared__ int rows_s[128];

    const int t    = threadIdx.x;
    const int wv   = t >> 6;
    const int l    = t & 63;
    const int wm   = wv >> 1;
    const int wn   = wv & 1;
    const int m    = l & 15;
    const int quad = l >> 4;

    const int  srow8   = l >> 3;
    const int  schunk  = (l & 7) ^ srow8;
    const size_t laneoff_w = (size_t)srow8 * D + schunk * 8;
    const bool stz   = (wv < 2);
    const int  sbase = (wv & 1) * 64;

    const int n     = *cnt;
    const int njobs = ((n + 127) >> 7) << 3;

    for (int job = blockIdx.x; job < njobs; job += gridDim.x) {
        const int tile = job >> 3;
        const int nb   = job & 7;
        __syncthreads();                     // LDS reuse guard (implicit full drain)
        if (t < 128) {
            const int fi = tile * 128 + t;
            rows_s[t] = (fi < n) ? flagged[fi] : -1;
        }
        __syncthreads();

        int zrow[8];
        #pragma unroll
        for (int i = 0; i < 8; ++i) {
            const int rr = rows_s[sbase + i * 8 + srow8];
            zrow[i] = rr < 0 ? 0 : rr;
        }
        int   rowid[4][4];
        float thr[4][4];
        #pragma unroll
        for (int mi = 0; mi < 4; ++mi)
            #pragma unroll
            for (int r = 0; r < 4; ++r) {
                const int rl = wm * 64 + mi * 16 + quad * 4 + r;
                const int ri = rows_s[rl];
                rowid[mi][r] = ri;
                thr[mi][r]   = (ri >= 0) ? m1g[ri] + TAU_SCREEN : -FLT_MAX;
            }

        f32x4 acc[4][4];
        #pragma unroll
        for (int mi = 0; mi < 4; ++mi)
            #pragma unroll
            for (int ni = 0; ni < 4; ++ni) acc[mi][ni] = (f32x4){0.f, 0.f, 0.f, 0.f};

        #define STAGEC(ks_, buf_) do {                                                \
            if (stz) {                                                                \
                unsigned short* ldsb_ = &zT[buf_][sbase * 64];                        \
                _Pragma("unroll")                                                     \
                for (int i_ = 0; i_ < 8; ++i_)                                        \
                    gl2lds16(zbf + (size_t)zrow[i_] * D + (ks_) * 64 + schunk * 8,    \
                             ldsb_ + i_ * 512);                                       \
            } else {                                                                  \
                unsigned short* ldsb_ = &wT[buf_][sbase * 64];                        \
                const unsigned short* gb_ =                                           \
                    wbf + (size_t)(nb * 128 + sbase) * D + (ks_) * 64;                \
                _Pragma("unroll")                                                     \
                for (int i_ = 0; i_ < 8; ++i_)                                        \
                    gl2lds16(gb_ + (size_t)i_ * 8 * D + laneoff_w, ldsb_ + i_ * 512); \
            }                                                                         \
        } while (0)

        STAGEC(0, 0);
        for (int ks = 0; ks < 4; ++ks) {
            const int cur = ks & 1;
            if (ks < 3) {
                STAGEC(ks + 1, cur ^ 1);
                asm volatile("s_waitcnt vmcnt(8) lgkmcnt(0)" ::: "memory");
            } else {
                asm volatile("s_waitcnt vmcnt(0) lgkmcnt(0)" ::: "memory");
            }
            asm volatile("s_barrier" ::: "memory");
            #pragma unroll
            for (int kk = 0; kk < 2; ++kk) {
                short8 a[4], b[4];
                const int ch = kk * 4 + quad;
                const int co = (ch ^ (m & 7)) * 8;
                #pragma unroll
                for (int mi = 0; mi < 4; ++mi)
                    a[mi] = *(const short8*)&zT[cur][(wm * 64 + mi * 16 + m) * 64 + co];
                #pragma unroll
                for (int ni = 0; ni < 4; ++ni)
                    b[ni] = *(const short8*)&wT[cur][(wn * 64 + ni * 16 + m) * 64 + co];
                #pragma unroll
                for (int mi = 0; mi < 4; ++mi)
                    #pragma unroll
                    for (int ni = 0; ni < 4; ++ni)
                        acc[mi][ni] = __builtin_amdgcn_mfma_f32_16x16x32_bf16(
                            a[mi], b[ni], acc[mi][ni], 0, 0, 0);
            }
            asm volatile("s_barrier" ::: "memory");
        }
        #undef STAGEC

        // inline exact eval on hits (~1 per thread per job)
        #pragma unroll
        for (int ni = 0; ni < 4; ++ni) {
            const int code = nb * 128 + wn * 64 + ni * 16 + m;
            const float c  = Cn[code];
            #pragma unroll
            for (int mi = 0; mi < 4; ++mi)
                #pragma unroll
                for (int r = 0; r < 4; ++r) {
                    const float v = fmaf(-2.0f, acc[mi][ni][r], c);
                    if (v < thr[mi][r]) {
                        const int row = rowid[mi][r];
                        const float d = np_exact_d(z, w, Cn, row, code);
                        const uint32_t bits = __float_as_uint(d);
                        const uint32_t ord  = (bits & 0x80000000u) ? ~bits
                                                                   : (bits | 0x80000000u);
                        const unsigned long long key =
                            ((unsigned long long)ord << 32) |
                            (unsigned long long)(uint32_t)code;
                        atomicMin(&packed[row], key);
                    }
                }
        }
    }
}

// ---------------- unpack refined indices (separate kernel: packed must be
// fully consumed before vq_gather overwrites its d_out region) ----------------
__global__ __launch_bounds__(256) void vq_unpack(const int* __restrict__ flagged,
                                                 const int* __restrict__ cnt,
                                                 const unsigned long long* __restrict__ packed,
                                                 int* __restrict__ idx) {
    const int n = *cnt;
    for (int g = blockIdx.x * 256 + threadIdx.x; g < n; g += gridDim.x * 256) {
        const int row = flagged[g];
        idx[row] = (int)(packed[row] & 0xffffffffull);
    }
}

// ---------------- gather ----------------
__global__ __launch_bounds__(256) void vq_gather(const float* __restrict__ w,
                                                 const int* __restrict__ idx,
                                                 float* __restrict__ outq,
                                                 float* __restrict__ outi) {
    const int t    = threadIdx.x;
    const int lane = t & 63;
    const int sub  = t >> 6;
    const int row0 = blockIdx.x * 128;
    #pragma unroll 4
    for (int it = 0; it < 32; ++it) {
        const int row = row0 + it * 4 + sub;
        const int j   = idx[row];
        ((float4*)outq)[(size_t)row * 64 + lane] = ((const float4*)w)[(size_t)j * 64 + lane];
        if (lane == 0) outi[row] = (float)j;
    }
}

extern "C" void kernel_launch(void* const* d_in, const int* in_sizes, int n_in,
                              void* d_out, int out_size, void* d_ws, size_t ws_size,
                              hipStream_t stream) {
    const float* z = (const float*)d_in[0];
    const float* w = (const float*)d_in[1];
    float* outq = (float*)d_out;
    float* outi = outq + (size_t)NROWS * D;

    // scratch inside d_out (all dead before vq_gather):
    //   zbf   [0, 32MB)        bf16 z
    //   wbf   [32MB, 32.5MB)   bf16 w
    //   Cn    [32.5MB, +4KB)   |w|^2
    //   m1g   [35MB, +256KB)   per-row screen min1
    //   packed[35.5MB, +512KB) per-row (ordered-d, code) u64
    unsigned short*     zbf    = (unsigned short*)d_out;
    unsigned short*     wbf    = (unsigned short*)((char*)d_out + 33554432);
    float*              Cn     = (float*)((char*)d_out + 34078720);
    float*              m1g    = (float*)((char*)d_out + 36700160);
    unsigned long long* packed = (unsigned long long*)((char*)d_out + 37224448);

    char* ws      = (char*)d_ws;
    int*  idx     = (int*)ws;
    int*  flagged = (int*)(ws + 262144);
    int*  cnt     = (int*)(ws + 524288);

    vq_prep<<<8580, 256, 0, stream>>>(z, zbf, w, wbf, Cn, cnt, packed);
    vq_screen<<<NROWS / 128, 512, 0, stream>>>(zbf, wbf, Cn, idx, flagged, cnt, m1g);
    vq_candx<<<512, 256, 0, stream>>>(zbf, wbf, Cn, m1g, flagged, cnt, z, w, packed);
    vq_unpack<<<64, 256, 0, stream>>>(flagged, cnt, packed, idx);
    vq_gather<<<NROWS / 128, 256, 0, stream>>>(w, idx, outq, outi);
}

// Round 9
// 221.030 us; speedup vs baseline: 1.2031x; 1.2031x over previous
//
#include <hip/hip_runtime.h>
#include <hip/hip_bf16.h>
#include <stdint.h>
#include <float.h>

// VQ quantize: z[65536,256] f32, weight[1024,256] f32.
// ref (numpy fp32): d = fl32(fl32(A - 2*B) + C); idx = argmax(-d) (first-index ties).
// Outputs (float32, concat): quantized [65536*256], indices [65536].
//
// Pipeline:
//   1) vq_prep: fused {init cnt/pcnt/packed, z->bf16, w->bf16, Cn=|w|^2 exact}
//   2) vq_screen: bf16 MFMA GEMM screen, 512-thread blocks (8 waves, wave tile
//      32x64, vmcnt(4)); counted-vmcnt pipeline; epilogue after trailing barrier.
//      Geometry verified R8 (absmax 0).
//   3) vq_cand: (tile x nb) jobs, counted-vmcnt 4-step pipeline, LDS-aggregated
//      emission (R7-proven: list aliased over dead tiles, ONE global atomic per
//      block). R8 LESSON: do NOT inline exact eval under the emission predicate
//      -- sparse hits across 64 unrolled iterations serialize full dot products
//      under near-empty exec masks (87us). Keep exact dense in its own kernel.
//   4) vq_exact: one lane per pair, dense (all lanes active); bit-exact
//      numpy-fp32 chain; atomicMin packed (ordered-d, code).
//   5) vq_unpack: separate (R5 lesson: packed in d_out, consumed before gather).
//   6) vq_gather.

constexpr int NROWS = 65536;
constexpr int D     = 256;
constexpr int CODES = 1024;

constexpr float TAU_SCREEN = 2.5e-4f;
constexpr int   MAXPAIRS   = 7000000;

typedef __attribute__((ext_vector_type(8))) short short8;   // 8 bf16 = 4 VGPR
typedef __attribute__((ext_vector_type(4))) float f32x4;

// global -> LDS async 16B/lane: per-lane global src, wave-uniform LDS base,
// HW writes lane l -> base + l*16 (m97/m104 semantics).
__device__ __forceinline__ void gl2lds16(const unsigned short* g, unsigned short* l) {
    __builtin_amdgcn_global_load_lds(
        (const __attribute__((address_space(1))) void*)g,
        (__attribute__((address_space(3))) void*)l, 16, 0, 0);
}

// ---------------- fp32 -> bf16 (RNE) ----------------
__device__ __forceinline__ unsigned short f2bf(float x) {
    union { __hip_bfloat16 h; unsigned short u; } c;
    c.h = __float2bfloat16(x);
    return c.u;
}

__device__ __forceinline__ void cvt8(const float* __restrict__ src,
                                     unsigned short* __restrict__ dst, int i) {
    const float4* s = (const float4*)src + (size_t)i * 2;
    float4 a = s[0], b = s[1];
    union { unsigned short u[8]; uint4 v; } p;
    p.u[0] = f2bf(a.x); p.u[1] = f2bf(a.y); p.u[2] = f2bf(a.z); p.u[3] = f2bf(a.w);
    p.u[4] = f2bf(b.x); p.u[5] = f2bf(b.y); p.u[6] = f2bf(b.z); p.u[7] = f2bf(b.w);
    *(uint4*)(dst + (size_t)i * 8) = p.v;
}

// ---------------- fused prep ----------------
// blocks [0,8192): z->bf16 | [8192,8320): w->bf16 | [8320,8324): rownorm |
// [8324,8580): packed init + counters. rownorm in EXACT numpy pairwise order.
__global__ __launch_bounds__(256) void vq_prep(const float* __restrict__ z,
                                               unsigned short* __restrict__ zbf,
                                               const float* __restrict__ w,
                                               unsigned short* __restrict__ wbf,
                                               float* __restrict__ Cn,
                                               int* __restrict__ cnt,
                                               int* __restrict__ pcnt,
                                               unsigned long long* __restrict__ packed) {
    const int b = blockIdx.x;
    const int t = threadIdx.x;
    if (b < 8192) {
        cvt8(z, zbf, b * 256 + t);
    } else if (b < 8320) {
        cvt8(w, wbf, (b - 8192) * 256 + t);
    } else if (b < 8324) {
        const int row = (b - 8320) * 256 + t;
        const float4* p = (const float4*)(w + (size_t)row * D);
        float res[2];
        #pragma unroll
        for (int h = 0; h < 2; ++h) {
            float r[8];
            #pragma unroll
            for (int j = 0; j < 8; ++j) r[j] = 0.f;
            #pragma unroll 4
            for (int mm = 0; mm < 16; ++mm) {
                const float4 v0 = p[h * 32 + mm * 2];
                const float4 v1 = p[h * 32 + mm * 2 + 1];
                r[0] = __fadd_rn(r[0], __fmul_rn(v0.x, v0.x));
                r[1] = __fadd_rn(r[1], __fmul_rn(v0.y, v0.y));
                r[2] = __fadd_rn(r[2], __fmul_rn(v0.z, v0.z));
                r[3] = __fadd_rn(r[3], __fmul_rn(v0.w, v0.w));
                r[4] = __fadd_rn(r[4], __fmul_rn(v1.x, v1.x));
                r[5] = __fadd_rn(r[5], __fmul_rn(v1.y, v1.y));
                r[6] = __fadd_rn(r[6], __fmul_rn(v1.z, v1.z));
                r[7] = __fadd_rn(r[7], __fmul_rn(v1.w, v1.w));
            }
            res[h] = __fadd_rn(__fadd_rn(__fadd_rn(r[0], r[1]), __fadd_rn(r[2], r[3])),
                               __fadd_rn(__fadd_rn(r[4], r[5]), __fadd_rn(r[6], r[7])));
        }
        Cn[row] = __fadd_rn(res[0], res[1]);
    } else {
        const int i = (b - 8324) * 256 + t;
        packed[i] = ~0ull;
        if (i == 0) { *cnt = 0; *pcnt = 0; }
    }
}

// ---------------- bf16 MFMA screen (8-wave blocks, counted vmcnt; R8-verified) ----
// 128 rows x 1024 codes per block; 32 steps (nb-major, ks-minor), dbuf LDS.
// 8 waves: wave wv -> rows [(wv>>1)*32,+32) x cols [(wv&1)*64,+64) per nb.
// Staging: 32 units of 1KB (16 z + 16 w); wave wv stages units 4wv..4wv+3;
// LINEAR LDS dest + pre-swizzled global source.
__global__ __launch_bounds__(512, 4) void vq_screen(const unsigned short* __restrict__ zbf,
                                                    const unsigned short* __restrict__ wbf,
                                                    const float* __restrict__ Cn,
                                                    int* __restrict__ idx_out,
                                                    int* __restrict__ flagged,
                                                    int* __restrict__ cnt,
                                                    float* __restrict__ m1_out) {
    __shared__ unsigned short zT[2][128 * 64];
    __shared__ unsigned short wT[2][128 * 64];
    __shared__ float Cs[1024];
    __shared__ float rm1s[2][128];
    __shared__ float rm2s[2][128];
    __shared__ int   ris[2][128];

    const int t    = threadIdx.x;
    const int wv   = t >> 6;          // wave 0..7
    const int l    = t & 63;
    const int wm   = wv >> 1;         // row quarter 0..3
    const int wn   = wv & 1;          // col half
    const int m    = l & 15;
    const int quad = l >> 4;
    const int row0 = blockIdx.x * 128;

    const int  srow8   = l >> 3;
    const int  schunk  = (l & 7) ^ srow8;
    const size_t laneoff = (size_t)srow8 * D + schunk * 8;

    for (int i = t; i < 1024; i += 512) Cs[i] = Cn[i];

    float m1[2][4], m2[2][4];
    int   bi[2][4];
    f32x4 acc[2][4];
    #pragma unroll
    for (int mi = 0; mi < 2; ++mi)
        #pragma unroll
        for (int r = 0; r < 4; ++r) {
            m1[mi][r] = FLT_MAX; m2[mi][r] = FLT_MAX; bi[mi][r] = 0;
            acc[mi][r] = (f32x4){0.f, 0.f, 0.f, 0.f};
        }

    #define STAGE(s_, buf_) do {                                                    \
        const int nb_ = (s_) >> 2, ks_ = (s_) & 3;                                  \
        _Pragma("unroll")                                                           \
        for (int i_ = 0; i_ < 4; ++i_) {                                            \
            const int u_ = wv * 4 + i_;                                             \
            if (u_ < 16)                                                            \
                gl2lds16(zbf + (size_t)(row0 + u_ * 8) * D + ks_ * 64 + laneoff,    \
                         &zT[buf_][u_ * 512]);                                      \
            else                                                                    \
                gl2lds16(wbf + (size_t)(nb_ * 128 + (u_ - 16) * 8) * D + ks_ * 64   \
                             + laneoff,                                             \
                         &wT[buf_][(u_ - 16) * 512]);                               \
        }                                                                           \
    } while (0)

    STAGE(0, 0);

    for (int s = 0; s < 32; ++s) {
        const int cur = s & 1;
        if (s < 31) {
            STAGE(s + 1, cur ^ 1);
            asm volatile("s_waitcnt vmcnt(4) lgkmcnt(0)" ::: "memory");
        } else {
            asm volatile("s_waitcnt vmcnt(0) lgkmcnt(0)" ::: "memory");
        }
        asm volatile("s_barrier" ::: "memory");

        #pragma unroll
        for (int kk = 0; kk < 2; ++kk) {
            short8 a[2], b[4];
            const int ch = kk * 4 + quad;
            const int co = (ch ^ (m & 7)) * 8;
            #pragma unroll
            for (int mi = 0; mi < 2; ++mi)
                a[mi] = *(const short8*)&zT[cur][(wm * 32 + mi * 16 + m) * 64 + co];
            #pragma unroll
            for (int ni = 0; ni < 4; ++ni)
                b[ni] = *(const short8*)&wT[cur][(wn * 64 + ni * 16 + m) * 64 + co];
            #pragma unroll
            for (int mi = 0; mi < 2; ++mi)
                #pragma unroll
                for (int ni = 0; ni < 4; ++ni)
                    acc[mi][ni] = __builtin_amdgcn_mfma_f32_16x16x32_bf16(
                        a[mi], b[ni], acc[mi][ni], 0, 0, 0);
        }
        asm volatile("s_barrier" ::: "memory");

        if ((s & 3) == 3) {          // nb complete: registers + Cs only -> after barrier
            const int nb = s >> 2;
            #pragma unroll
            for (int ni = 0; ni < 4; ++ni) {
                const int code = nb * 128 + wn * 64 + ni * 16 + m;
                const float c  = Cs[code];
                #pragma unroll
                for (int mi = 0; mi < 2; ++mi)
                    #pragma unroll
                    for (int r = 0; r < 4; ++r) {
                        const float v = fmaf(-2.0f, acc[mi][ni][r], c);
                        if (v < m1[mi][r]) { m2[mi][r] = m1[mi][r]; m1[mi][r] = v; bi[mi][r] = code; }
                        else if (v < m2[mi][r]) m2[mi][r] = v;
                        acc[mi][ni][r] = 0.f;
                    }
            }
        }
    }
    #undef STAGE

    // reduce across the 16 col-lanes (xor 1,2,4,8 varies l&15 only).
    #pragma unroll
    for (int mi = 0; mi < 2; ++mi)
        #pragma unroll
        for (int r = 0; r < 4; ++r) {
            float a1 = m1[mi][r], a2 = m2[mi][r];
            int   ai = bi[mi][r];
            #pragma unroll
            for (int off = 1; off <= 8; off <<= 1) {
                float o1 = __shfl_xor(a1, off, 64);
                float o2 = __shfl_xor(a2, off, 64);
                int   oi = __shfl_xor(ai, off, 64);
                float n2 = fminf(a2, o2);
                if (o1 < a1) { n2 = fminf(n2, a1); a1 = o1; ai = oi; }
                else n2 = fminf(n2, o1);
                a2 = n2;
            }
            m1[mi][r] = a1; m2[mi][r] = a2; bi[mi][r] = ai;
        }

    if (m == 0) {
        #pragma unroll
        for (int mi = 0; mi < 2; ++mi)
            #pragma unroll
            for (int r = 0; r < 4; ++r) {
                const int rl = wm * 32 + mi * 16 + quad * 4 + r;
                rm1s[wn][rl] = m1[mi][r];
                rm2s[wn][rl] = m2[mi][r];
                ris[wn][rl]  = bi[mi][r];
            }
    }
    __syncthreads();
    if (t < 128) {
        float a1 = rm1s[0][t], a2 = rm2s[0][t];
        int   ai = ris[0][t];
        const float o1 = rm1s[1][t], o2 = rm2s[1][t];
        const int   oi = ris[1][t];
        float n2 = fminf(a2, o2);
        if (o1 < a1) { n2 = fminf(n2, a1); a1 = o1; ai = oi; }
        else n2 = fminf(n2, o1);
        a2 = n2;
        const int row = row0 + t;
        idx_out[row] = ai;
        m1_out[row]  = a1;
        if (a2 - a1 < TAU_SCREEN) {
            int p = atomicAdd(cnt, 1);
            flagged[p] = row;
        }
    }
}

// ---------------- candidate emit (R7-proven: LDS-agg emission) ----------------
// Job = (128 gathered flagged rows) x (one 128-code nb); ~296 jobs on 512 blocks.
// 4-step counted-vmcnt pipeline; emission into LDS list aliased over DEAD tiles
// (capacity 16384 = full tile => cannot overflow), ONE global atomic per block.
__global__ __launch_bounds__(256, 2) void vq_cand(const unsigned short* __restrict__ zbf,
                                                  const unsigned short* __restrict__ wbf,
                                                  const float* __restrict__ Cn,
                                                  const float* __restrict__ m1g,
                                                  const int* __restrict__ flagged,
                                                  const int* __restrict__ cnt,
                                                  uint32_t* __restrict__ pairs,
                                                  int* __restrict__ pcnt) {
    __shared__ union SM {
        struct { unsigned short zT[2][128 * 64]; unsigned short wT[2][128 * 64]; } tl;
        uint32_t list[16384];
    } sm;
    __shared__ int rows_s[128];
    __shared__ int lcnt;
    __shared__ int gbase;

    const int t    = threadIdx.x;
    const int wv   = t >> 6;
    const int l    = t & 63;
    const int wm   = wv >> 1;
    const int wn   = wv & 1;
    const int m    = l & 15;
    const int quad = l >> 4;

    const int  srow8   = l >> 3;
    const int  schunk  = (l & 7) ^ srow8;
    const size_t laneoff_w = (size_t)srow8 * D + schunk * 8;
    const bool stz   = (wv < 2);
    const int  sbase = (wv & 1) * 64;

    const int n     = *cnt;
    const int njobs = ((n + 127) >> 7) << 3;

    for (int job = blockIdx.x; job < njobs; job += gridDim.x) {
        const int tile = job >> 3;
        const int nb   = job & 7;
        __syncthreads();
        if (t < 128) {
            const int fi = tile * 128 + t;
            rows_s[t] = (fi < n) ? flagged[fi] : -1;
        }
        if (t == 0) lcnt = 0;
        __syncthreads();

        int zrow[8];
        #pragma unroll
        for (int i = 0; i < 8; ++i) {
            const int rr = rows_s[sbase + i * 8 + srow8];
            zrow[i] = rr < 0 ? 0 : rr;
        }
        int   rowid[4][4];
        float thr[4][4];
        #pragma unroll
        for (int mi = 0; mi < 4; ++mi)
            #pragma unroll
            for (int r = 0; r < 4; ++r) {
                const int rl = wm * 64 + mi * 16 + quad * 4 + r;
                const int ri = rows_s[rl];
                rowid[mi][r] = ri;
                thr[mi][r]   = (ri >= 0) ? m1g[ri] + TAU_SCREEN : -FLT_MAX;
            }

        f32x4 acc[4][4];
        #pragma unroll
        for (int mi = 0; mi < 4; ++mi)
            #pragma unroll
            for (int ni = 0; ni < 4; ++ni) acc[mi][ni] = (f32x4){0.f, 0.f, 0.f, 0.f};

        #define STAGEC(ks_, buf_) do {                                                \
            if (stz) {                                                                \
                unsigned short* ldsb_ = &sm.tl.zT[buf_][sbase * 64];                  \
                _Pragma("unroll")                                                     \
                for (int i_ = 0; i_ < 8; ++i_)                                        \
                    gl2lds16(zbf + (size_t)zrow[i_] * D + (ks_) * 64 + schunk * 8,    \
                             ldsb_ + i_ * 512);                                       \
            } else {                                                                  \
                unsigned short* ldsb_ = &sm.tl.wT[buf_][sbase * 64];                  \
                const unsigned short* gb_ =                                           \
                    wbf + (size_t)(nb * 128 + sbase) * D + (ks_) * 64;                \
                _Pragma("unroll")                                                     \
                for (int i_ = 0; i_ < 8; ++i_)                                        \
                    gl2lds16(gb_ + (size_t)i_ * 8 * D + laneoff_w, ldsb_ + i_ * 512); \
            }                                                                         \
        } while (0)

        STAGEC(0, 0);
        for (int ks = 0; ks < 4; ++ks) {
            const int cur = ks & 1;
            if (ks < 3) {
                STAGEC(ks + 1, cur ^ 1);
                asm volatile("s_waitcnt vmcnt(8) lgkmcnt(0)" ::: "memory");
            } else {
                asm volatile("s_waitcnt vmcnt(0) lgkmcnt(0)" ::: "memory");
            }
            asm volatile("s_barrier" ::: "memory");
            #pragma unroll
            for (int kk = 0; kk < 2; ++kk) {
                short8 a[4], b[4];
                const int ch = kk * 4 + quad;
                const int co = (ch ^ (m & 7)) * 8;
                #pragma unroll
                for (int mi = 0; mi < 4; ++mi)
                    a[mi] = *(const short8*)&sm.tl.zT[cur][(wm * 64 + mi * 16 + m) * 64 + co];
                #pragma unroll
                for (int ni = 0; ni < 4; ++ni)
                    b[ni] = *(const short8*)&sm.tl.wT[cur][(wn * 64 + ni * 16 + m) * 64 + co];
                #pragma unroll
                for (int mi = 0; mi < 4; ++mi)
                    #pragma unroll
                    for (int ni = 0; ni < 4; ++ni)
                        acc[mi][ni] = __builtin_amdgcn_mfma_f32_16x16x32_bf16(
                            a[mi], b[ni], acc[mi][ni], 0, 0, 0);
            }
            asm volatile("s_barrier" ::: "memory");
        }
        #undef STAGEC
        // tiles dead from here; sm.list may alias them.

        #pragma unroll
        for (int ni = 0; ni < 4; ++ni) {
            const int code = nb * 128 + wn * 64 + ni * 16 + m;
            const float c  = Cn[code];
            #pragma unroll
            for (int mi = 0; mi < 4; ++mi)
                #pragma unroll
                for (int r = 0; r < 4; ++r) {
                    const float v = fmaf(-2.0f, acc[mi][ni][r], c);
                    if (v < thr[mi][r]) {
                        const int p = atomicAdd(&lcnt, 1);   // LDS atomic
                        sm.list[p] = ((uint32_t)rowid[mi][r] << 16) | (uint32_t)code;
                    }
                }
        }
        __syncthreads();
        if (t == 0) gbase = atomicAdd(pcnt, lcnt);           // ONE global atomic
        __syncthreads();
        const int nc = lcnt;
        const int gb = gbase;
        for (int i = t; i < nc; i += 256) {
            const int p = gb + i;
            if (p < MAXPAIRS) pairs[p] = sm.list[i];
        }
    }
}

// ---------------- exact eval: one lane per (row,code) pair (dense) ----------------
__global__ __launch_bounds__(256) void vq_exact(const float* __restrict__ z,
                                                const float* __restrict__ w,
                                                const float* __restrict__ Cn,
                                                const uint32_t* __restrict__ pairs,
                                                const int* __restrict__ pcnt,
                                                unsigned long long* __restrict__ packed) {
    const int np0 = *pcnt;
    const int np  = np0 < MAXPAIRS ? np0 : MAXPAIRS;
    for (int g = blockIdx.x * 256 + threadIdx.x; g < np; g += gridDim.x * 256) {
        const uint32_t pr = pairs[g];
        const int row  = (int)(pr >> 16);
        const int code = (int)(pr & 0xffffu);
        const float4* zp = (const float4*)(z + (size_t)row * D);
        const float4* wp = (const float4*)(w + (size_t)code * D);
        float B = 0.f;
        float res[2];
        #pragma unroll
        for (int b = 0; b < 2; ++b) {
            float r[8];
            #pragma unroll
            for (int j = 0; j < 8; ++j) r[j] = 0.f;
            #pragma unroll 4
            for (int mm = 0; mm < 16; ++mm) {
                const float4 z0 = zp[b * 32 + mm * 2];
                const float4 z1 = zp[b * 32 + mm * 2 + 1];
                const float4 w0 = wp[b * 32 + mm * 2];
                const float4 w1 = wp[b * 32 + mm * 2 + 1];
                r[0] = __fadd_rn(r[0], __fmul_rn(z0.x, z0.x));
                r[1] = __fadd_rn(r[1], __fmul_rn(z0.y, z0.y));
                r[2] = __fadd_rn(r[2], __fmul_rn(z0.z, z0.z));
                r[3] = __fadd_rn(r[3], __fmul_rn(z0.w, z0.w));
                r[4] = __fadd_rn(r[4], __fmul_rn(z1.x, z1.x));
                r[5] = __fadd_rn(r[5], __fmul_rn(z1.y, z1.y));
                r[6] = __fadd_rn(r[6], __fmul_rn(z1.z, z1.z));
                r[7] = __fadd_rn(r[7], __fmul_rn(z1.w, z1.w));
                B = fmaf(z0.x, w0.x, B); B = fmaf(z0.y, w0.y, B);
                B = fmaf(z0.z, w0.z, B); B = fmaf(z0.w, w0.w, B);
                B = fmaf(z1.x, w1.x, B); B = fmaf(z1.y, w1.y, B);
                B = fmaf(z1.z, w1.z, B); B = fmaf(z1.w, w1.w, B);
            }
            res[b] = __fadd_rn(__fadd_rn(__fadd_rn(r[0], r[1]), __fadd_rn(r[2], r[3])),
                               __fadd_rn(__fadd_rn(r[4], r[5]), __fadd_rn(r[6], r[7])));
        }
        const float A = __fadd_rn(res[0], res[1]);
        const float d = __fadd_rn(__fsub_rn(A, __fmul_rn(2.0f, B)), Cn[code]);
        const uint32_t bits = __float_as_uint(d);
        const uint32_t ord  = (bits & 0x80000000u) ? ~bits : (bits | 0x80000000u);
        const unsigned long long key =
            ((unsigned long long)ord << 32) | (unsigned long long)(uint32_t)code;
        atomicMin(&packed[row], key);
    }
}

// ---------------- unpack refined indices ----------------
__global__ __launch_bounds__(256) void vq_unpack(const int* __restrict__ flagged,
                                                 const int* __restrict__ cnt,
                                                 const unsigned long long* __restrict__ packed,
                                                 int* __restrict__ idx) {
    const int n = *cnt;
    for (int g = blockIdx.x * 256 + threadIdx.x; g < n; g += gridDim.x * 256) {
        const int row = flagged[g];
        idx[row] = (int)(packed[row] & 0xffffffffull);
    }
}

// ---------------- gather ----------------
__global__ __launch_bounds__(256) void vq_gather(const float* __restrict__ w,
                                                 const int* __restrict__ idx,
                                                 float* __restrict__ outq,
                                                 float* __restrict__ outi) {
    const int t    = threadIdx.x;
    const int lane = t & 63;
    const int sub  = t >> 6;
    const int row0 = blockIdx.x * 128;
    #pragma unroll 4
    for (int it = 0; it < 32; ++it) {
        const int row = row0 + it * 4 + sub;
        const int j   = idx[row];
        ((float4*)outq)[(size_t)row * 64 + lane] = ((const float4*)w)[(size_t)j * 64 + lane];
        if (lane == 0) outi[row] = (float)j;
    }
}

extern "C" void kernel_launch(void* const* d_in, const int* in_sizes, int n_in,
                              void* d_out, int out_size, void* d_ws, size_t ws_size,
                              hipStream_t stream) {
    const float* z = (const float*)d_in[0];
    const float* w = (const float*)d_in[1];
    float* outq = (float*)d_out;
    float* outi = outq + (size_t)NROWS * D;

    // scratch inside d_out (all dead before vq_gather):
    //   zbf   [0, 32MB)        bf16 z
    //   wbf   [32MB, 32.5MB)   bf16 w
    //   Cn    [32.5MB, +4KB)   |w|^2
    //   m1g   [35MB, +256KB)   per-row screen min1
    //   packed[35.5MB, +512KB) per-row (ordered-d, code) u64
    //   pairs [36MB, ...)      candidate (row<<16|code) u32, cap MAXPAIRS
    unsigned short*     zbf    = (unsigned short*)d_out;
    unsigned short*     wbf    = (unsigned short*)((char*)d_out + 33554432);
    float*              Cn     = (float*)((char*)d_out + 34078720);
    float*              m1g    = (float*)((char*)d_out + 36700160);
    unsigned long long* packed = (unsigned long long*)((char*)d_out + 37224448);
    uint32_t*           pairs  = (uint32_t*)((char*)d_out + 37748736);

    char* ws      = (char*)d_ws;
    int*  idx     = (int*)ws;
    int*  flagged = (int*)(ws + 262144);
    int*  cnt     = (int*)(ws + 524288);
    int*  pcnt    = (int*)(ws + 524292);

    vq_prep<<<8580, 256, 0, stream>>>(z, zbf, w, wbf, Cn, cnt, pcnt, packed);
    vq_screen<<<NROWS / 128, 512, 0, stream>>>(zbf, wbf, Cn, idx, flagged, cnt, m1g);
    vq_cand<<<512, 256, 0, stream>>>(zbf, wbf, Cn, m1g, flagged, cnt, pairs, pcnt);
    vq_exact<<<256, 256, 0, stream>>>(z, w, Cn, pairs, pcnt, packed);
    vq_unpack<<<64, 256, 0, stream>>>(flagged, cnt, packed, idx);
    vq_gather<<<NROWS / 128, 256, 0, stream>>>(w, idx, outq, outi);
}